// Round 1
// baseline (1485.795 us; speedup 1.0000x reference)
//
#include <hip/hip_runtime.h>
#include <math.h>

#define THREADS 256
#define VOCAB 50257

// Per-element update: argmax of (l+g) carrying the logit, plus online softmax of l.
#define PROCESS(lval, gval, idx)                                   \
    do {                                                           \
        float _v = (lval) + (gval);                                \
        if (_v > bestv) { bestv = _v; bestidx = (idx); bestlogit = (lval); } \
        float _l = (lval);                                         \
        if (_l <= m) {                                             \
            s += __expf(_l - m);                                   \
        } else {                                                   \
            s = s * __expf(m - _l) + 1.0f;                         \
            m = _l;                                                \
        }                                                          \
    } while (0)

__global__ __launch_bounds__(THREADS)
void gumbel_sample_kernel(const float* __restrict__ logits,
                          const float* __restrict__ gumbel,
                          float* __restrict__ out_idx,   // [B] index as float
                          float* __restrict__ out_logp,  // [B]
                          int vocab)
{
    const int row = blockIdx.x;
    const long long base = (long long)row * vocab;
    const float* __restrict__ lrow = logits + base;
    const float* __restrict__ grow = gumbel + base;
    const int tid = threadIdx.x;

    // Thread-local state
    float bestv = -INFINITY;
    int   bestidx = 0;
    float bestlogit = 0.0f;
    float m = -INFINITY;   // running max of logits
    float s = 0.0f;        // running sum exp(l - m)

    // Row base alignment: base % 4 == row % 4 (vocab % 4 == 1). Peel to 16B.
    const int head = (4 - ((int)(base & 3))) & 3;

    // Head scalars
    if (tid < head) {
        PROCESS(lrow[tid], grow[tid], tid);
    }

    // Aligned vector body
    const int nvec = (vocab - head) >> 2;
    const float4* __restrict__ lv = (const float4*)(lrow + head);
    const float4* __restrict__ gv = (const float4*)(grow + head);
    for (int i = tid; i < nvec; i += THREADS) {
        float4 l = lv[i];
        float4 g = gv[i];
        int idx0 = head + 4 * i;
        PROCESS(l.x, g.x, idx0 + 0);
        PROCESS(l.y, g.y, idx0 + 1);
        PROCESS(l.z, g.z, idx0 + 2);
        PROCESS(l.w, g.w, idx0 + 3);
    }

    // Tail scalars
    const int tail_start = head + 4 * nvec;
    const int tail = vocab - tail_start;
    if (tid < tail) {
        int idx = tail_start + tid;
        PROCESS(lrow[idx], grow[idx], idx);
    }

    // ---- Wave (64-lane) shuffle reduction ----
    #pragma unroll
    for (int off = 32; off > 0; off >>= 1) {
        float om = __shfl_down(m, off);
        float os = __shfl_down(s, off);
        float mn = fmaxf(m, om);
        s = s * __expf(m - mn) + os * __expf(om - mn);
        m = mn;

        float ov = __shfl_down(bestv, off);
        int   oi = __shfl_down(bestidx, off);
        float ol = __shfl_down(bestlogit, off);
        if (ov > bestv || (ov == bestv && oi < bestidx)) {
            bestv = ov; bestidx = oi; bestlogit = ol;
        }
    }

    // ---- Cross-wave reduction via LDS (4 waves) ----
    __shared__ float sm[THREADS / 64];
    __shared__ float ss[THREADS / 64];
    __shared__ float sv[THREADS / 64];
    __shared__ float sl[THREADS / 64];
    __shared__ int   si[THREADS / 64];

    const int wave = tid >> 6;
    const int lane = tid & 63;
    if (lane == 0) {
        sm[wave] = m; ss[wave] = s;
        sv[wave] = bestv; si[wave] = bestidx; sl[wave] = bestlogit;
    }
    __syncthreads();

    if (tid == 0) {
        #pragma unroll
        for (int w = 1; w < THREADS / 64; ++w) {
            float om = sm[w], os = ss[w];
            float mn = fmaxf(m, om);
            s = s * __expf(m - mn) + os * __expf(om - mn);
            m = mn;
            float ov = sv[w]; int oi = si[w]; float ol = sl[w];
            if (ov > bestv || (ov == bestv && oi < bestidx)) {
                bestv = ov; bestidx = oi; bestlogit = ol;
            }
        }
        out_idx[row]  = (float)bestidx;
        out_logp[row] = bestlogit - m - logf(s);
    }
}

extern "C" void kernel_launch(void* const* d_in, const int* in_sizes, int n_in,
                              void* d_out, int out_size, void* d_ws, size_t ws_size,
                              hipStream_t stream) {
    const float* logits = (const float*)d_in[0];
    const float* gumbel = (const float*)d_in[1];
    float* out = (float*)d_out;

    const int vocab = VOCAB;
    const int batch = in_sizes[0] / vocab;

    gumbel_sample_kernel<<<batch, THREADS, 0, stream>>>(
        logits, gumbel, out /* indices */, out + batch /* logp */, vocab);
}